// Round 5
// baseline (175.967 us; speedup 1.0000x reference)
//
#include <hip/hip_runtime.h>
#include <math.h>

typedef unsigned short ushort_t;
typedef __attribute__((ext_vector_type(8))) short short8;
typedef __attribute__((ext_vector_type(4))) float f32x4;

#define NTILES 12   // 12 tiles x 32 positions = 384 >= 361

// ws ushort layout (bf16 MFMA A-fragments, lane-major 16B blocks):
//   L1 @0      : 16 outsub x 9 kstep x 64 lane x 8 = 73728   (K=288: 256 NDI + 16 u(colsum) + 16 v(-rowsum))
//   L2 @73728  :  8 outsub x 8 kstep x 64 lane x 8 = 32768
//   L3 @106496 :  4 outsub x 4 kstep x 64 lane x 8 =  8192
//   L4 @114688 :  2 kstep x 64 lane x 8            =  1024 (rows 4..15 zero)
#define WS_W_USHORTS 115712

__device__ inline float bf2f(ushort_t h) { return __uint_as_float(((unsigned)h) << 16); }
__device__ inline ushort_t f2bf(float f) {
    unsigned u = __float_as_uint(f);
    return (ushort_t)((u + 0x7FFFu + ((u >> 16) & 1u)) >> 16);
}
__device__ inline unsigned pkbf(float f0, float f1) {
    unsigned a = __float_as_uint(f0) + 0x8000u;
    unsigned b = __float_as_uint(f1) + 0x8000u;
    return __builtin_amdgcn_perm(b, a, 0x07060302u);
}
// leaky = max(v, 0.01v): v>=0 -> v, v<0 -> 0.01v  (2 VALU ops, packable)
__device__ inline float leaky(float v) { return fmaxf(v, 0.01f * v); }

__global__ void pack_weights(const float* __restrict__ w1, const float* __restrict__ w2,
                             const float* __restrict__ w3, const float* __restrict__ w4,
                             ushort_t* __restrict__ ws) {
    const int idx = blockIdx.x * 256 + threadIdx.x;
    if (idx >= WS_W_USHORTS) return;
    float val = 0.f;
    if (idx < 73728) {
        const int j = idx & 7, lane = (idx >> 3) & 63, blk = idx >> 9;
        const int ks = blk % 9, os = blk / 9;
        const int m = lane & 15, q = lane >> 4;
        const int row = os * 16 + m;
        if (ks < 8) {
            const int k = ks * 32 + q * 8 + j;
            const int i1 = k >> 4, j1 = k & 15;
            val = w1[row * 512 + i1 * 32 + j1 * 2 + 1];      // NDI weight (c=1)
        } else {
            const int sub = q * 8 + j;
            if (sub < 16) {                                  // u coeff: colsum of DI weights
                const int j1 = sub;
                float s = 0.f;
                #pragma unroll
                for (int i1 = 0; i1 < 16; ++i1) s += w1[row * 512 + i1 * 32 + j1 * 2];
                val = s;
            } else {                                         // v coeff: -rowsum of DI weights
                const int i1 = sub - 16;
                float s = 0.f;
                #pragma unroll
                for (int j1 = 0; j1 < 16; ++j1) s += w1[row * 512 + i1 * 32 + j1 * 2];
                val = -s;
            }
        }
    } else if (idx < 106496) {
        const int l = idx - 73728;
        const int j = l & 7, lane = (l >> 3) & 63, blk = l >> 9;
        const int ks = blk & 7, os = blk >> 3;
        const int m = lane & 15, q = lane >> 4;
        val = w2[(os * 16 + m) * 256 + ks * 32 + q * 8 + j];
    } else if (idx < 114688) {
        const int l = idx - 106496;
        const int j = l & 7, lane = (l >> 3) & 63, blk = l >> 9;
        const int ks = blk & 3, os = blk >> 2;
        const int m = lane & 15, q = lane >> 4;
        val = w3[(os * 16 + m) * 128 + ks * 32 + q * 8 + j];
    } else {
        const int l = idx - 114688;
        const int j = l & 7, lane = (l >> 3) & 63, ks = l >> 9;
        const int m = lane & 15, q = lane >> 4;
        val = (m < 4) ? w4[m * 64 + ks * 32 + q * 8 + j] : 0.f;
    }
    ws[idx] = f2bf(val);
}

// LDS (ushort units), XOR-swizzled: element (row, oct) at base + row*STR + ((oct ^ (row&7))*8)
//   ts  @0      32 x 320 (288 ch + swizzle room)  = 10240   } aliased: h2s @0 32x128 = 4096
//   h1s @10240  32 x 256                          =  8192   } aliased: m3s @10240 (2048),
//                                                            ebuf @12288 (128 f32), abuf @12544 (4 f32),
//                                                            mbuf @10240 (772 f32, after loop)
//   xp  @18432  308 f32                           =   616
// total 19048 ush = 38096 B -> 4 blocks/CU if VGPR<=128
template <int NS>
__global__ __launch_bounds__(256, 3) void fused_mfma(
    const float* __restrict__ x, const ushort_t* __restrict__ ws,
    const float* __restrict__ b1, const float* __restrict__ b2,
    const float* __restrict__ b3, const float* __restrict__ b4,
    float* __restrict__ part)
{
    __shared__ __align__(16) ushort_t sm[19048];
    ushort_t* const ts   = sm;
    ushort_t* const h2s  = sm;                    // aliases ts (dead after L1)
    ushort_t* const h1s  = sm + 10240;
    ushort_t* const m3s  = sm + 10240;            // aliases h1s (dead after L2)
    float*   const ebuf  = (float*)(sm + 12288);  // 128 e-values (aliases h1s tail)
    float*   const abuf  = (float*)(sm + 12544);  // 4 alphas
    float*   const xp    = (float*)(sm + 18432);

    constexpr int SH  = (NS == 4) ? 2 : ((NS == 2) ? 1 : 0);
    constexpr int TPS = (NTILES + NS - 1) / NS;
    const int tid = threadIdx.x;
    const int s   = blockIdx.x & (NS - 1);
    const int bb  = blockIdx.x >> SH;
    const int t0  = s * TPS;
    const int t1  = (t0 + TPS < NTILES) ? (t0 + TPS) : NTILES;

    const int wid  = tid >> 6;
    const int lane = tid & 63;
    const int n0   = lane & 15;
    const int qi   = lane >> 4;
    const int sx   = n0 & 7;
    const int row0 = qi * 4;

    for (int jj = tid; jj < 308; jj += 256) {
        float v = 0.f;
        const int src = jj - 2;
        if (src >= 0 && src < 300) v = x[bb * 300 + src];
        xp[jj] = v;
    }

    const short8* wf1 = (const short8*)(ws);
    const short8* wf2 = (const short8*)(ws + 73728);
    const short8* wf3 = (const short8*)(ws + 106496);
    const short8* wf4 = (const short8*)(ws + 114688);

    // per-thread bias fragments (hoisted; init MFMA acc with these)
    f32x4 bv1[4], bv2[2], bv3, bv4;
    #pragma unroll
    for (int jo = 0; jo < 4; ++jo) bv1[jo] = *(const f32x4*)&b1[(wid * 4 + jo) * 16 + row0];
    #pragma unroll
    for (int jo = 0; jo < 2; ++jo) bv2[jo] = *(const f32x4*)&b2[(wid * 2 + jo) * 16 + row0];
    bv3 = *(const f32x4*)&b3[wid * 16 + row0];
    bv4 = *(const f32x4*)&b4[0];

    // softmax accumulation identity: thread = (cp 0..63 = ch pair, qt 0..3 = pos quarter)
    const int cp = tid & 63;
    const int qt = tid >> 6;
    const int qq = cp >> 4;            // head for this thread's channels
    float A0 = 0.f, A1 = 0.f, Ss = 0.f;
    float Mq[4] = {-1e30f, -1e30f, -1e30f, -1e30f};   // maintained by wave 0 only

    __syncthreads();

    for (int tile = t0; tile < t1; ++tile) {
        const int pos0 = tile * 32;

        // ---- build t tile: thread = (p = tid&31, i1b = tid>>5), i1 in {i1b, i1b+8} ----
        {
            const int p   = tid & 31;
            const int i1b = tid >> 5;
            int posg = pos0 + p; if (posg > 360) posg = 360;
            const int hh = posg / 19;
            const int ww = posg - 19 * hh;
            const int base = p * 320;
            const int psw  = p & 7;
            float u[16];
            #pragma unroll
            for (int j1 = 0; j1 < 16; ++j1) u[j1] = xp[j1 * 19 + ww];
            #pragma unroll
            for (int ii = 0; ii < 2; ++ii) {
                const int i1 = i1b + ii * 8;
                const float v = xp[i1 * 19 + hh];
                #pragma unroll
                for (int j1 = 0; j1 < 16; j1 += 2) {
                    const float nd0 = (u[j1] - v)     * __builtin_amdgcn_rcpf(u[j1] + v + 1e-5f);
                    const float nd1 = (u[j1 + 1] - v) * __builtin_amdgcn_rcpf(u[j1 + 1] + v + 1e-5f);
                    const int oct = i1 * 2 + (j1 >> 3);
                    *(unsigned*)&ts[base + ((oct ^ psw) << 3) + (j1 & 7)] = pkbf(nd0, nd1);
                }
            }
            if (i1b == 0) {  // u/v extension columns (ch 256..287)
                #pragma unroll
                for (int j1 = 0; j1 < 16; j1 += 2) {
                    const int oct = 32 + (j1 >> 3);
                    *(unsigned*)&ts[base + ((oct ^ psw) << 3) + (j1 & 7)] = pkbf(u[j1], u[j1 + 1]);
                }
                #pragma unroll
                for (int i1 = 0; i1 < 16; i1 += 2) {
                    const float v0 = xp[i1 * 19 + hh];
                    const float v1 = xp[(i1 + 1) * 19 + hh];
                    const int oct = 34 + (i1 >> 3);
                    *(unsigned*)&ts[base + ((oct ^ psw) << 3) + (i1 & 7)] = pkbf(v0, v1);
                }
            }
        }
        __syncthreads();

        // ---- layer 1: 256 outs, K=288 (9 ksteps); wave = 4 outsubs x 2 possubs ----
        f32x4 acc1[4][2];
        {
            #pragma unroll
            for (int jo = 0; jo < 4; ++jo) { acc1[jo][0] = bv1[jo]; acc1[jo][1] = bv1[jo]; }
            const int tb0 = n0 * 320;
            const int tb1 = tb0 + 16 * 320;
            const int wbase = wid * 2304 + lane;
            #pragma unroll 3
            for (int ks = 0; ks < 9; ++ks) {
                const int oct = ks * 4 + qi;
                const short8 bb0 = *(const short8*)&ts[tb0 + ((oct ^ sx) << 3)];
                const short8 bb1 = *(const short8*)&ts[tb1 + ((oct ^ sx) << 3)];
                #pragma unroll
                for (int jo = 0; jo < 4; ++jo) {
                    const short8 a = wf1[wbase + (jo * 9 + ks) * 64];
                    acc1[jo][0] = __builtin_amdgcn_mfma_f32_16x16x32_bf16(a, bb0, acc1[jo][0], 0, 0, 0);
                    acc1[jo][1] = __builtin_amdgcn_mfma_f32_16x16x32_bf16(a, bb1, acc1[jo][1], 0, 0, 0);
                }
            }
        }
        __syncthreads();   // everyone done reading ts -> safe to write h1s AND later h2s(=ts)
        {
            #pragma unroll
            for (int jo = 0; jo < 4; ++jo) {
                const int out0 = (wid * 4 + jo) * 16 + row0;
                #pragma unroll
                for (int ps = 0; ps < 2; ++ps) {
                    const f32x4 a4 = acc1[jo][ps];
                    uint2 pk;
                    pk.x = pkbf(leaky(a4.x), leaky(a4.y));
                    pk.y = pkbf(leaky(a4.z), leaky(a4.w));
                    *(uint2*)&h1s[(ps * 16 + n0) * 256 + (((out0 >> 3) ^ sx) << 3) + (out0 & 7)] = pk;
                }
            }
        }
        __syncthreads();

        // ---- layer 2: 128 outs, K=256; wave = 2 outsubs x 2 possubs; writes h2s(=ts) ----
        {
            f32x4 acc[2][2];
            #pragma unroll
            for (int jo = 0; jo < 2; ++jo) { acc[jo][0] = bv2[jo]; acc[jo][1] = bv2[jo]; }
            const int hb0 = n0 * 256;
            const int hb1 = hb0 + 16 * 256;
            const int wbase = wid * 1024 + lane;
            #pragma unroll 4
            for (int ks = 0; ks < 8; ++ks) {
                const int oct = ks * 4 + qi;
                const short8 bb0 = *(const short8*)&h1s[hb0 + ((oct ^ sx) << 3)];
                const short8 bb1 = *(const short8*)&h1s[hb1 + ((oct ^ sx) << 3)];
                #pragma unroll
                for (int jo = 0; jo < 2; ++jo) {
                    const short8 a = wf2[wbase + (jo * 8 + ks) * 64];
                    acc[jo][0] = __builtin_amdgcn_mfma_f32_16x16x32_bf16(a, bb0, acc[jo][0], 0, 0, 0);
                    acc[jo][1] = __builtin_amdgcn_mfma_f32_16x16x32_bf16(a, bb1, acc[jo][1], 0, 0, 0);
                }
            }
            #pragma unroll
            for (int jo = 0; jo < 2; ++jo) {
                const int out0 = (wid * 2 + jo) * 16 + row0;
                #pragma unroll
                for (int ps = 0; ps < 2; ++ps) {
                    const f32x4 a4 = acc[jo][ps];
                    uint2 pk;
                    pk.x = pkbf(leaky(a4.x), leaky(a4.y));
                    pk.y = pkbf(leaky(a4.z), leaky(a4.w));
                    *(uint2*)&h2s[(ps * 16 + n0) * 128 + (((out0 >> 3) ^ sx) << 3) + (out0 & 7)] = pk;
                }
            }
        }
        __syncthreads();

        // ---- layer 3: 64 outs, K=128; wave = 1 outsub x 2 possubs (writes m3s = h1s alias) ----
        {
            f32x4 acc[2] = {bv3, bv3};
            const int cb0 = n0 * 128;
            const int cb1 = cb0 + 16 * 128;
            #pragma unroll
            for (int ks = 0; ks < 4; ++ks) {
                const int oct = ks * 4 + qi;
                const short8 bb0 = *(const short8*)&h2s[cb0 + ((oct ^ sx) << 3)];
                const short8 bb1 = *(const short8*)&h2s[cb1 + ((oct ^ sx) << 3)];
                const short8 a = wf3[(wid * 4 + ks) * 64 + lane];
                acc[0] = __builtin_amdgcn_mfma_f32_16x16x32_bf16(a, bb0, acc[0], 0, 0, 0);
                acc[1] = __builtin_amdgcn_mfma_f32_16x16x32_bf16(a, bb1, acc[1], 0, 0, 0);
            }
            const int out0 = wid * 16 + row0;
            #pragma unroll
            for (int ps = 0; ps < 2; ++ps) {
                const f32x4 a4 = acc[ps];
                uint2 pk;
                pk.x = pkbf(fmaxf(a4.x, 0.f), fmaxf(a4.y, 0.f));
                pk.y = pkbf(fmaxf(a4.z, 0.f), fmaxf(a4.w, 0.f));
                *(uint2*)&m3s[(ps * 16 + n0) * 64 + (((out0 >> 3) ^ sx) << 3) + (out0 & 7)] = pk;
            }
        }
        __syncthreads();

        // ---- layer 4 + exp (wave 0 only): logits -> per-q max (shfl butterfly) -> e,alpha to LDS ----
        if (wid == 0) {
            f32x4 acc[2] = {bv4, bv4};
            const int mb0 = n0 * 64;
            const int mb1 = mb0 + 16 * 64;
            #pragma unroll
            for (int ks = 0; ks < 2; ++ks) {
                const int oct = ks * 4 + qi;
                const short8 bb0 = *(const short8*)&m3s[mb0 + ((oct ^ sx) << 3)];
                const short8 bb1 = *(const short8*)&m3s[mb1 + ((oct ^ sx) << 3)];
                const short8 a = wf4[ks * 64 + lane];
                acc[0] = __builtin_amdgcn_mfma_f32_16x16x32_bf16(a, bb0, acc[0], 0, 0, 0);
                acc[1] = __builtin_amdgcn_mfma_f32_16x16x32_bf16(a, bb1, acc[1], 0, 0, 0);
            }
            // lanes 0..15 hold rows(q) 0..3 for pos = lane (possub0) and lane+16 (possub1)
            const bool bad0 = (pos0 + lane) > 360;          // meaningful for lane<16
            const bool bad1 = (pos0 + 16 + lane) > 360;
            float l0[4], l1[4];
            l0[0] = bad0 ? -1e30f : fmaxf(acc[0].x, 0.f);
            l0[1] = bad0 ? -1e30f : fmaxf(acc[0].y, 0.f);
            l0[2] = bad0 ? -1e30f : fmaxf(acc[0].z, 0.f);
            l0[3] = bad0 ? -1e30f : fmaxf(acc[0].w, 0.f);
            l1[0] = bad1 ? -1e30f : fmaxf(acc[1].x, 0.f);
            l1[1] = bad1 ? -1e30f : fmaxf(acc[1].y, 0.f);
            l1[2] = bad1 ? -1e30f : fmaxf(acc[1].z, 0.f);
            l1[3] = bad1 ? -1e30f : fmaxf(acc[1].w, 0.f);
            #pragma unroll
            for (int q = 0; q < 4; ++q) {
                float tm = fmaxf(l0[q], l1[q]);
                tm = fmaxf(tm, __shfl_xor(tm, 1, 64));
                tm = fmaxf(tm, __shfl_xor(tm, 2, 64));
                tm = fmaxf(tm, __shfl_xor(tm, 4, 64));
                tm = fmaxf(tm, __shfl_xor(tm, 8, 64));
                const float nM = fmaxf(Mq[q], tm);
                const float al = __expf(Mq[q] - nM);
                Mq[q] = nM;
                const float e0 = __expf(l0[q] - nM);
                const float e1 = __expf(l1[q] - nM);
                if (lane < 16) {
                    ebuf[q * 32 + lane]      = e0;
                    ebuf[q * 32 + 16 + lane] = e1;
                }
                if (lane == 0) abuf[q] = al;
            }
        }
        __syncthreads();

        // ---- accumulation: thread = (cp, qt); 2 channels x 8 positions ----
        {
            const float alpha = abuf[qq];
            A0 *= alpha; A1 *= alpha; Ss *= alpha;
            const int oc4 = cp >> 2;
            const int elo = (cp & 3) * 2;
            #pragma unroll
            for (int pp = 0; pp < 8; ++pp) {
                const int p = qt * 8 + pp;
                const float e = ebuf[qq * 32 + p];
                const unsigned hp = *(const unsigned*)&h2s[p * 128 + ((oc4 ^ (p & 7)) << 3) + elo];
                const float f0 = __uint_as_float(hp << 16);
                const float f1 = __uint_as_float(hp & 0xFFFF0000u);
                A0 += e * f0;
                A1 += e * f1;
                Ss += e;
            }
        }
        __syncthreads();   // protect h2s(=ts) and ebuf(=h1s) before next tile overwrites
    }

    // combine 4 quarters via LDS, write partials (M,S,A) for cross-block merge
    float* mbuf = (float*)(sm + 10240);   // 772 f32, everything else dead
    mbuf[qt * 64 + cp]        = A0;
    mbuf[256 + qt * 64 + cp]  = A1;
    mbuf[512 + qt * 64 + cp]  = Ss;
    if (wid == 0 && lane < 4) mbuf[768 + lane] = Mq[lane];
    __syncthreads();
    if (tid < 128) {
        const int ch = tid, cpf = ch >> 1, par = ch & 1;
        float Af = 0.f, Sf = 0.f;
        #pragma unroll
        for (int t = 0; t < 4; ++t) {
            Af += mbuf[par * 256 + t * 64 + cpf];
            Sf += mbuf[512 + t * 64 + cpf];
        }
        const float Mf = mbuf[768 + (ch >> 5)];
        const int pb  = (s * 512 + bb) * 128 + ch;
        const int sep = NS * 512 * 128;
        part[pb]           = Mf;
        part[pb + sep]     = Sf;
        part[pb + 2 * sep] = Af;
    }
}

template <int NS>
__global__ void merge_out(const float* __restrict__ part, float* __restrict__ out) {
    const int idx = blockIdx.x * 256 + threadIdx.x;
    if (idx >= 512 * 128) return;
    const int bb = idx >> 7, ch = idx & 127;
    const int sep = NS * 512 * 128;
    float Mf = -1e30f;
    #pragma unroll
    for (int s = 0; s < NS; ++s) Mf = fmaxf(Mf, part[(s * 512 + bb) * 128 + ch]);
    float Sf = 0.f, Af = 0.f;
    #pragma unroll
    for (int s = 0; s < NS; ++s) {
        const int pb = (s * 512 + bb) * 128 + ch;
        const float e = __expf(part[pb] - Mf);
        Sf += part[pb + sep] * e;
        Af += part[pb + 2 * sep] * e;
    }
    out[idx] = Af / Sf;
}

// ---------------- f32 scalar fallback (known-correct, ws-free) ----------------
__global__ __launch_bounds__(256, 2) void fallback_fused(
    const float* __restrict__ x,
    const float* __restrict__ w1, const float* __restrict__ b1,
    const float* __restrict__ w2, const float* __restrict__ b2,
    const float* __restrict__ w3, const float* __restrict__ b3,
    const float* __restrict__ w4, const float* __restrict__ b4,
    float* __restrict__ out)
{
    __shared__ float smf[14644];
    float* const xp  = smf;
    float* const ts  = smf + 308;
    float* const h1s = smf + 8500;
    float* const h2s = smf + 12596;
    float* const m3s = ts;
    float* const lgs = ts + 1024;

    const int tid = threadIdx.x;
    const int b   = blockIdx.x;
    for (int j = tid; j < 308; j += 256) {
        float v = 0.f;
        const int src = j - 2;
        if (src >= 0 && src < 300) v = x[b * 300 + src];
        xp[j] = v;
    }
    __syncthreads();
    const int q = tid >> 5, dd = tid & 31;
    float M = -1e30f, S = 0.f, A = 0.f;
    for (int tile = 0; tile < 23; ++tile) {
        const int pos0 = tile * 16;
        {
            const int p = tid & 15, kk0 = tid >> 4;
            const int pos = pos0 + p;
            const bool valid = (pos < 361);
            const int hh = valid ? (pos / 19) : 0;
            const int ww = valid ? (pos - hh * 19) : 0;
            #pragma unroll
            for (int i = 0; i < 16; ++i) {
                const int kk = kk0 + (i << 4);
                const int i1 = kk >> 4, j1 = kk & 15;
                float di = 0.f, ndi = 0.f;
                if (valid) {
                    const float u = xp[j1 * 19 + ww];
                    const float v = xp[i1 * 19 + hh];
                    di = u - v; ndi = di / (u + v + 1e-5f);
                }
                ts[(kk << 5) + p] = di;
                ts[(kk << 5) + 16 + p] = ndi;
            }
        }
        __syncthreads();
        {
            const int o = tid;
            float acc[16];
            const float bias = b1[o];
            #pragma unroll
            for (int p = 0; p < 16; ++p) acc[p] = bias;
            for (int k = 0; k < 512; ++k) {
                const float wv = w1[o * 512 + k];
                #pragma unroll
                for (int p = 0; p < 16; ++p) acc[p] += wv * ts[(k << 4) + p];
            }
            #pragma unroll
            for (int p = 0; p < 16; ++p) h1s[(o << 4) + p] = (acc[p] >= 0.f) ? acc[p] : 0.01f * acc[p];
        }
        __syncthreads();
        {
            const int o2 = tid & 127, pb = (tid >> 7) << 3;
            float acc[8];
            const float bias = b2[o2];
            #pragma unroll
            for (int j = 0; j < 8; ++j) acc[j] = bias;
            for (int k = 0; k < 256; ++k) {
                const float wv = w2[o2 * 256 + k];
                #pragma unroll
                for (int j = 0; j < 8; ++j) acc[j] += wv * h1s[(k << 4) + pb + j];
            }
            #pragma unroll
            for (int j = 0; j < 8; ++j) h2s[(o2 << 4) + pb + j] = (acc[j] >= 0.f) ? acc[j] : 0.01f * acc[j];
        }
        __syncthreads();
        {
            const int o3 = tid & 63, pb = (tid >> 6) << 2;
            float acc[4];
            const float bias = b3[o3];
            #pragma unroll
            for (int j = 0; j < 4; ++j) acc[j] = bias;
            for (int k = 0; k < 128; ++k) {
                const float wv = w3[o3 * 128 + k];
                #pragma unroll
                for (int j = 0; j < 4; ++j) acc[j] += wv * h2s[(k << 4) + pb + j];
            }
            #pragma unroll
            for (int j = 0; j < 4; ++j) m3s[(o3 << 4) + pb + j] = fmaxf(acc[j], 0.f);
        }
        __syncthreads();
        if (tid < 64) {
            const int o4 = tid >> 4, p = tid & 15;
            float a = b4[o4];
            for (int k = 0; k < 64; ++k) a += w4[o4 * 64 + k] * m3s[(k << 4) + p];
            a = fmaxf(a, 0.f);
            if (pos0 + p >= 361) a = -1e30f;
            lgs[(o4 << 4) + p] = a;
        }
        __syncthreads();
        if (tid < 128) {
            float l[16];
            #pragma unroll
            for (int p = 0; p < 16; ++p) l[p] = lgs[(q << 4) + p];
            float tmax = l[0];
            #pragma unroll
            for (int p = 1; p < 16; ++p) tmax = fmaxf(tmax, l[p]);
            const float newM = fmaxf(M, tmax);
            const float alpha = __expf(M - newM);
            float ssum = 0.f, asum = 0.f;
            #pragma unroll
            for (int p = 0; p < 16; ++p) {
                const float e = __expf(l[p] - newM);
                ssum += e;
                asum += e * h2s[(((q << 5) + dd) << 4) + p];
            }
            S = S * alpha + ssum; A = A * alpha + asum; M = newM;
        }
        __syncthreads();
    }
    if (tid < 128) out[(b << 7) + tid] = A / S;
}

extern "C" void kernel_launch(void* const* d_in, const int* in_sizes, int n_in,
                              void* d_out, int out_size, void* d_ws, size_t ws_size,
                              hipStream_t stream) {
    const float* x  = (const float*)d_in[0];
    const float* w1 = (const float*)d_in[1];
    const float* b1 = (const float*)d_in[2];
    const float* w2 = (const float*)d_in[3];
    const float* b2 = (const float*)d_in[4];
    const float* w3 = (const float*)d_in[5];
    const float* b3 = (const float*)d_in[6];
    const float* w4 = (const float*)d_in[7];
    const float* b4 = (const float*)d_in[8];
    float* out = (float*)d_out;

    const size_t wbytes  = (size_t)WS_W_USHORTS * sizeof(ushort_t);
    const size_t pbytes1 = (size_t)3 * 512 * 128 * sizeof(float);
    ushort_t* ws = (ushort_t*)d_ws;
    float* partf = (float*)((char*)d_ws + wbytes);

    const int packBlocks = (WS_W_USHORTS + 255) / 256;
    if (ws_size >= wbytes + 4 * pbytes1) {
        pack_weights<<<packBlocks, 256, 0, stream>>>(w1, w2, w3, w4, ws);
        fused_mfma<4><<<2048, 256, 0, stream>>>(x, ws, b1, b2, b3, b4, partf);
        merge_out<4><<<256, 256, 0, stream>>>(partf, out);
    } else if (ws_size >= wbytes + 2 * pbytes1) {
        pack_weights<<<packBlocks, 256, 0, stream>>>(w1, w2, w3, w4, ws);
        fused_mfma<2><<<1024, 256, 0, stream>>>(x, ws, b1, b2, b3, b4, partf);
        merge_out<2><<<256, 256, 0, stream>>>(partf, out);
    } else if (ws_size >= wbytes + pbytes1) {
        pack_weights<<<packBlocks, 256, 0, stream>>>(w1, w2, w3, w4, ws);
        fused_mfma<1><<<512, 256, 0, stream>>>(x, ws, b1, b2, b3, b4, partf);
        merge_out<1><<<256, 256, 0, stream>>>(partf, out);
    } else {
        fallback_fused<<<512, 256, 0, stream>>>(x, w1, b1, w2, b2, w3, b3, w4, b4, out);
    }
}

// Round 6
// 168.998 us; speedup vs baseline: 1.0412x; 1.0412x over previous
//
#include <hip/hip_runtime.h>
#include <math.h>

typedef unsigned short ushort_t;
typedef __attribute__((ext_vector_type(8))) short short8;
typedef __attribute__((ext_vector_type(4))) float f32x4;

#define NTILES 12   // 12 tiles x 32 positions = 384 >= 361

// ws ushort layout (bf16 MFMA A-fragments, lane-major 16B blocks):
//   L1 @0      : 16 outsub x 9 kstep x 64 lane x 8 = 73728   (K=288: 256 NDI + 16 u(colsum) + 16 v(-rowsum))
//   L2 @73728  :  8 outsub x 8 kstep x 64 lane x 8 = 32768
//   L3 @106496 :  4 outsub x 4 kstep x 64 lane x 8 =  8192
//   L4 @114688 :  2 kstep x 64 lane x 8            =  1024 (rows 4..15 zero)
#define WS_W_USHORTS 115712

__device__ inline ushort_t f2bf(float f) {
    unsigned u = __float_as_uint(f);
    return (ushort_t)((u + 0x7FFFu + ((u >> 16) & 1u)) >> 16);
}
__device__ inline unsigned pkbf(float f0, float f1) {
    unsigned a = __float_as_uint(f0) + 0x8000u;
    unsigned b = __float_as_uint(f1) + 0x8000u;
    return __builtin_amdgcn_perm(b, a, 0x07060302u);
}
// leaky = max(v, 0.01v)
__device__ inline float leaky(float v) { return fmaxf(v, 0.01f * v); }

__global__ void pack_weights(const float* __restrict__ w1, const float* __restrict__ w2,
                             const float* __restrict__ w3, const float* __restrict__ w4,
                             ushort_t* __restrict__ ws) {
    const int idx = blockIdx.x * 256 + threadIdx.x;
    if (idx >= WS_W_USHORTS) return;
    float val = 0.f;
    if (idx < 73728) {
        const int j = idx & 7, lane = (idx >> 3) & 63, blk = idx >> 9;
        const int ks = blk % 9, os = blk / 9;
        const int m = lane & 15, q = lane >> 4;
        const int row = os * 16 + m;
        if (ks < 8) {
            const int k = ks * 32 + q * 8 + j;
            const int i1 = k >> 4, j1 = k & 15;
            val = w1[row * 512 + i1 * 32 + j1 * 2 + 1];      // NDI weight (c=1)
        } else {
            const int sub = q * 8 + j;
            if (sub < 16) {                                  // u coeff: colsum of DI weights
                const int j1 = sub;
                float s = 0.f;
                #pragma unroll
                for (int i1 = 0; i1 < 16; ++i1) s += w1[row * 512 + i1 * 32 + j1 * 2];
                val = s;
            } else {                                         // v coeff: -rowsum of DI weights
                const int i1 = sub - 16;
                float s = 0.f;
                #pragma unroll
                for (int j1 = 0; j1 < 16; ++j1) s += w1[row * 512 + i1 * 32 + j1 * 2];
                val = -s;
            }
        }
    } else if (idx < 106496) {
        const int l = idx - 73728;
        const int j = l & 7, lane = (l >> 3) & 63, blk = l >> 9;
        const int ks = blk & 7, os = blk >> 3;
        const int m = lane & 15, q = lane >> 4;
        val = w2[(os * 16 + m) * 256 + ks * 32 + q * 8 + j];
    } else if (idx < 114688) {
        const int l = idx - 106496;
        const int j = l & 7, lane = (l >> 3) & 63, blk = l >> 9;
        const int ks = blk & 3, os = blk >> 2;
        const int m = lane & 15, q = lane >> 4;
        val = w3[(os * 16 + m) * 128 + ks * 32 + q * 8 + j];
    } else {
        const int l = idx - 114688;
        const int j = l & 7, lane = (l >> 3) & 63, ks = l >> 9;
        const int m = lane & 15, q = lane >> 4;
        val = (m < 4) ? w4[m * 64 + ks * 32 + q * 8 + j] : 0.f;
    }
    ws[idx] = f2bf(val);
}

// LDS (ushort units), XOR-swizzled: element (row, oct) at base + row*STR + ((oct ^ (row&7))*8)
//   ts   @0      32 x 320 (288 ch used)  = 10240  } h2s aliases @0, 32x128 = 4096 (ts dead after L1;
//                                                   h2s dead after L3 -> no trailing barrier)
//   h1s  @10240  32 x 256               =  8192   } m3s aliases @10240 (2048); ebuf @12288 (128 f32)
//   xp   @18432  308 f32                =   616
// total 19048 ush = 38096 B -> 4 blocks/CU if VGPR <= 128
template <int NS>
__global__ __launch_bounds__(256, 3) void fused_mfma(
    const float* __restrict__ x, const ushort_t* __restrict__ ws,
    const float* __restrict__ b1, const float* __restrict__ b2,
    const float* __restrict__ b3, const float* __restrict__ b4,
    float* __restrict__ partA, float* __restrict__ partS)
{
    __shared__ __align__(16) ushort_t sm[19048];
    ushort_t* const ts   = sm;
    ushort_t* const h2s  = sm;                    // aliases ts
    ushort_t* const h1s  = sm + 10240;
    ushort_t* const m3s  = sm + 10240;            // aliases h1s
    float*   const ebuf  = (float*)(sm + 12288);  // 128 f32 e-values (aliases h1s tail)
    float*   const xp    = (float*)(sm + 18432);

    constexpr int SH  = (NS == 4) ? 2 : ((NS == 2) ? 1 : 0);
    constexpr int TPS = (NTILES + NS - 1) / NS;
    const int tid = threadIdx.x;
    const int s   = blockIdx.x & (NS - 1);
    const int bb  = blockIdx.x >> SH;
    const int t0  = s * TPS;
    const int t1  = (t0 + TPS < NTILES) ? (t0 + TPS) : NTILES;

    const int wid  = tid >> 6;
    const int lane = tid & 63;
    const int n0   = lane & 15;
    const int qi   = lane >> 4;
    const int sx   = n0 & 7;
    const int row0 = qi * 4;

    for (int jj = tid; jj < 308; jj += 256) {
        float v = 0.f;
        const int src = jj - 2;
        if (src >= 0 && src < 300) v = x[bb * 300 + src];
        xp[jj] = v;
    }

    const short8* wf1 = (const short8*)(ws);
    const short8* wf2 = (const short8*)(ws + 73728);
    const short8* wf3 = (const short8*)(ws + 106496);
    const short8* wf4 = (const short8*)(ws + 114688);

    // hoisted bias fragments
    f32x4 bv1[4], bv2[2], bv3, bv4;
    #pragma unroll
    for (int jo = 0; jo < 4; ++jo) bv1[jo] = *(const f32x4*)&b1[(wid * 4 + jo) * 16 + row0];
    #pragma unroll
    for (int jo = 0; jo < 2; ++jo) bv2[jo] = *(const f32x4*)&b2[(wid * 2 + jo) * 16 + row0];
    bv3 = *(const f32x4*)&b3[wid * 16 + row0];
    bv4 = *(const f32x4*)&b4[0];

    // softmax accumulators (in C-frag layout): A[jo][r], plus Ss = partial sum of e
    f32x4 Afr[2] = {{0.f, 0.f, 0.f, 0.f}, {0.f, 0.f, 0.f, 0.f}};
    float Ss = 0.f;

    __syncthreads();

    for (int tile = t0; tile < t1; ++tile) {
        const int pos0 = tile * 32;

        // ---- build t tile: thread = (p = tid&31, i1b = tid>>5), i1 in {i1b, i1b+8} ----
        {
            const int p   = tid & 31;
            const int i1b = tid >> 5;
            int posg = pos0 + p; if (posg > 360) posg = 360;
            const int hh = posg / 19;
            const int ww = posg - 19 * hh;
            const int base = p * 320;
            const int psw  = p & 7;
            float u[16];
            #pragma unroll
            for (int j1 = 0; j1 < 16; ++j1) u[j1] = xp[j1 * 19 + ww];
            #pragma unroll
            for (int ii = 0; ii < 2; ++ii) {
                const int i1 = i1b + ii * 8;
                const float v = xp[i1 * 19 + hh];
                #pragma unroll
                for (int j1 = 0; j1 < 16; j1 += 2) {
                    const float nd0 = (u[j1] - v)     * __builtin_amdgcn_rcpf(u[j1] + v + 1e-5f);
                    const float nd1 = (u[j1 + 1] - v) * __builtin_amdgcn_rcpf(u[j1 + 1] + v + 1e-5f);
                    const int oct = i1 * 2 + (j1 >> 3);
                    *(unsigned*)&ts[base + ((oct ^ psw) << 3) + (j1 & 7)] = pkbf(nd0, nd1);
                }
            }
            if (i1b == 0) {  // u/v extension columns (ch 256..287)
                #pragma unroll
                for (int j1 = 0; j1 < 16; j1 += 2) {
                    const int oct = 32 + (j1 >> 3);
                    *(unsigned*)&ts[base + ((oct ^ psw) << 3) + (j1 & 7)] = pkbf(u[j1], u[j1 + 1]);
                }
                #pragma unroll
                for (int i1 = 0; i1 < 16; i1 += 2) {
                    const float v0 = xp[i1 * 19 + hh];
                    const float v1 = xp[(i1 + 1) * 19 + hh];
                    const int oct = 34 + (i1 >> 3);
                    *(unsigned*)&ts[base + ((oct ^ psw) << 3) + (i1 & 7)] = pkbf(v0, v1);
                }
            }
        }
        __syncthreads();   // (1) ts ready

        // ---- layer 1: 256 outs, K=288 (9 ksteps); wave = 4 outsubs x 2 possubs ----
        {
            f32x4 acc[4][2];
            #pragma unroll
            for (int jo = 0; jo < 4; ++jo) { acc[jo][0] = bv1[jo]; acc[jo][1] = bv1[jo]; }
            const int tb0 = n0 * 320;
            const int tb1 = tb0 + 16 * 320;
            const int wbase = wid * 2304 + lane;
            #pragma unroll 3
            for (int ks = 0; ks < 9; ++ks) {
                const int oct = ks * 4 + qi;
                const short8 bb0 = *(const short8*)&ts[tb0 + ((oct ^ sx) << 3)];
                const short8 bb1 = *(const short8*)&ts[tb1 + ((oct ^ sx) << 3)];
                #pragma unroll
                for (int jo = 0; jo < 4; ++jo) {
                    const short8 a = wf1[wbase + (jo * 9 + ks) * 64];
                    acc[jo][0] = __builtin_amdgcn_mfma_f32_16x16x32_bf16(a, bb0, acc[jo][0], 0, 0, 0);
                    acc[jo][1] = __builtin_amdgcn_mfma_f32_16x16x32_bf16(a, bb1, acc[jo][1], 0, 0, 0);
                }
            }
            #pragma unroll
            for (int jo = 0; jo < 4; ++jo) {
                const int out0 = (wid * 4 + jo) * 16 + row0;
                #pragma unroll
                for (int ps = 0; ps < 2; ++ps) {
                    const f32x4 a4 = acc[jo][ps];
                    uint2 pk;
                    pk.x = pkbf(leaky(a4.x), leaky(a4.y));
                    pk.y = pkbf(leaky(a4.z), leaky(a4.w));
                    *(uint2*)&h1s[(ps * 16 + n0) * 256 + (((out0 >> 3) ^ sx) << 3) + (out0 & 7)] = pk;
                }
            }
        }
        __syncthreads();   // (2) h1s ready; also orders L1 ts-reads before L2 h2s(=ts) writes

        // ---- layer 2: 128 outs, K=256; wave = 2 outsubs x 2 possubs; C-frags kept in regs ----
        f32x4 h2f[2][2];   // post-leaky f32 h2 values (C-frag layout), used by accum phase
        {
            f32x4 acc[2][2];
            #pragma unroll
            for (int jo = 0; jo < 2; ++jo) { acc[jo][0] = bv2[jo]; acc[jo][1] = bv2[jo]; }
            const int hb0 = n0 * 256;
            const int hb1 = hb0 + 16 * 256;
            const int wbase = wid * 1024 + lane;
            #pragma unroll 4
            for (int ks = 0; ks < 8; ++ks) {
                const int oct = ks * 4 + qi;
                const short8 bb0 = *(const short8*)&h1s[hb0 + ((oct ^ sx) << 3)];
                const short8 bb1 = *(const short8*)&h1s[hb1 + ((oct ^ sx) << 3)];
                #pragma unroll
                for (int jo = 0; jo < 2; ++jo) {
                    const short8 a = wf2[wbase + (jo * 8 + ks) * 64];
                    acc[jo][0] = __builtin_amdgcn_mfma_f32_16x16x32_bf16(a, bb0, acc[jo][0], 0, 0, 0);
                    acc[jo][1] = __builtin_amdgcn_mfma_f32_16x16x32_bf16(a, bb1, acc[jo][1], 0, 0, 0);
                }
            }
            #pragma unroll
            for (int jo = 0; jo < 2; ++jo) {
                const int out0 = (wid * 2 + jo) * 16 + row0;
                #pragma unroll
                for (int ps = 0; ps < 2; ++ps) {
                    f32x4 a4 = acc[jo][ps];
                    a4.x = leaky(a4.x); a4.y = leaky(a4.y);
                    a4.z = leaky(a4.z); a4.w = leaky(a4.w);
                    h2f[jo][ps] = a4;
                    uint2 pk;
                    pk.x = pkbf(a4.x, a4.y);
                    pk.y = pkbf(a4.z, a4.w);
                    *(uint2*)&h2s[(ps * 16 + n0) * 128 + (((out0 >> 3) ^ sx) << 3) + (out0 & 7)] = pk;
                }
            }
        }
        __syncthreads();   // (3) h2s ready

        // ---- layer 3: 64 outs, K=128; wave = 1 outsub x 2 possubs (writes m3s = h1s alias) ----
        {
            f32x4 acc[2] = {bv3, bv3};
            const int cb0 = n0 * 128;
            const int cb1 = cb0 + 16 * 128;
            #pragma unroll
            for (int ks = 0; ks < 4; ++ks) {
                const int oct = ks * 4 + qi;
                const short8 bb0 = *(const short8*)&h2s[cb0 + ((oct ^ sx) << 3)];
                const short8 bb1 = *(const short8*)&h2s[cb1 + ((oct ^ sx) << 3)];
                const short8 a = wf3[(wid * 4 + ks) * 64 + lane];
                acc[0] = __builtin_amdgcn_mfma_f32_16x16x32_bf16(a, bb0, acc[0], 0, 0, 0);
                acc[1] = __builtin_amdgcn_mfma_f32_16x16x32_bf16(a, bb1, acc[1], 0, 0, 0);
            }
            const int out0 = wid * 16 + row0;
            #pragma unroll
            for (int ps = 0; ps < 2; ++ps) {
                const f32x4 a4 = acc[ps];
                uint2 pk;
                pk.x = pkbf(fmaxf(a4.x, 0.f), fmaxf(a4.y, 0.f));
                pk.y = pkbf(fmaxf(a4.z, 0.f), fmaxf(a4.w, 0.f));
                *(uint2*)&m3s[(ps * 16 + n0) * 64 + (((out0 >> 3) ^ sx) << 3) + (out0 & 7)] = pk;
            }
        }
        __syncthreads();   // (4) m3s ready; h2s dead from here (safe vs next-tile ts writes)

        // ---- layer 4 (wave 0): logits -> relu -> exp (fixed reference; relu bounds logits) ----
        if (wid == 0) {
            f32x4 acc[2] = {bv4, bv4};
            const int mb0 = n0 * 64;
            const int mb1 = mb0 + 16 * 64;
            #pragma unroll
            for (int ks = 0; ks < 2; ++ks) {
                const int oct = ks * 4 + qi;
                const short8 bb0 = *(const short8*)&m3s[mb0 + ((oct ^ sx) << 3)];
                const short8 bb1 = *(const short8*)&m3s[mb1 + ((oct ^ sx) << 3)];
                const short8 a = wf4[ks * 64 + lane];
                acc[0] = __builtin_amdgcn_mfma_f32_16x16x32_bf16(a, bb0, acc[0], 0, 0, 0);
                acc[1] = __builtin_amdgcn_mfma_f32_16x16x32_bf16(a, bb1, acc[1], 0, 0, 0);
            }
            if (lane < 16) {
                const bool bad0 = (pos0 + lane) > 360;
                const bool bad1 = (pos0 + 16 + lane) > 360;
                ebuf[0 * 32 + lane]      = bad0 ? 0.f : __expf(fmaxf(acc[0].x, 0.f));
                ebuf[1 * 32 + lane]      = bad0 ? 0.f : __expf(fmaxf(acc[0].y, 0.f));
                ebuf[2 * 32 + lane]      = bad0 ? 0.f : __expf(fmaxf(acc[0].z, 0.f));
                ebuf[3 * 32 + lane]      = bad0 ? 0.f : __expf(fmaxf(acc[0].w, 0.f));
                ebuf[0 * 32 + 16 + lane] = bad1 ? 0.f : __expf(fmaxf(acc[1].x, 0.f));
                ebuf[1 * 32 + 16 + lane] = bad1 ? 0.f : __expf(fmaxf(acc[1].y, 0.f));
                ebuf[2 * 32 + 16 + lane] = bad1 ? 0.f : __expf(fmaxf(acc[1].z, 0.f));
                ebuf[3 * 32 + 16 + lane] = bad1 ? 0.f : __expf(fmaxf(acc[1].w, 0.f));
            }
        }
        __syncthreads();   // (5) ebuf ready

        // ---- accumulate in C-frag layout: A[jo] += e0*h2f[jo][0] + e1*h2f[jo][1] ----
        {
            const float e0 = ebuf[wid * 32 + n0];        // head of this wave's outsubs = wid
            const float e1 = ebuf[wid * 32 + 16 + n0];
            #pragma unroll
            for (int jo = 0; jo < 2; ++jo) {
                Afr[jo].x += e0 * h2f[jo][0].x + e1 * h2f[jo][1].x;
                Afr[jo].y += e0 * h2f[jo][0].y + e1 * h2f[jo][1].y;
                Afr[jo].z += e0 * h2f[jo][0].z + e1 * h2f[jo][1].z;
                Afr[jo].w += e0 * h2f[jo][0].w + e1 * h2f[jo][1].w;
            }
            Ss += e0 + e1;
        }
        // no trailing barrier: next tile's (1) protects ts; ebuf rewritten only after next (4)
    }

    // cross-lane reduce over n0 (positions) via shfl butterfly
    #pragma unroll
    for (int bit = 1; bit < 16; bit <<= 1) {
        #pragma unroll
        for (int jo = 0; jo < 2; ++jo) {
            Afr[jo].x += __shfl_xor(Afr[jo].x, bit, 64);
            Afr[jo].y += __shfl_xor(Afr[jo].y, bit, 64);
            Afr[jo].z += __shfl_xor(Afr[jo].z, bit, 64);
            Afr[jo].w += __shfl_xor(Afr[jo].w, bit, 64);
        }
        Ss += __shfl_xor(Ss, bit, 64);
    }
    if (n0 == 0) {
        const int pbA = (s * 512 + bb) * 128;
        #pragma unroll
        for (int jo = 0; jo < 2; ++jo) {
            const int ch0 = (wid * 2 + jo) * 16 + qi * 4;
            partA[pbA + ch0]     = Afr[jo].x;
            partA[pbA + ch0 + 1] = Afr[jo].y;
            partA[pbA + ch0 + 2] = Afr[jo].z;
            partA[pbA + ch0 + 3] = Afr[jo].w;
        }
        if (qi == 0) partS[(s * 512 + bb) * 4 + wid] = Ss;
    }
}

template <int NS>
__global__ void merge_out(const float* __restrict__ partA, const float* __restrict__ partS,
                          float* __restrict__ out) {
    const int idx = blockIdx.x * 256 + threadIdx.x;
    if (idx >= 512 * 128) return;
    const int bb = idx >> 7, ch = idx & 127;
    const int q = ch >> 5;
    float Sf = 0.f, Af = 0.f;
    #pragma unroll
    for (int s = 0; s < NS; ++s) {
        Af += partA[(s * 512 + bb) * 128 + ch];
        Sf += partS[(s * 512 + bb) * 4 + q];
    }
    out[idx] = Af / Sf;
}

// ---------------- f32 scalar fallback (known-correct, ws-free) ----------------
__global__ __launch_bounds__(256, 2) void fallback_fused(
    const float* __restrict__ x,
    const float* __restrict__ w1, const float* __restrict__ b1,
    const float* __restrict__ w2, const float* __restrict__ b2,
    const float* __restrict__ w3, const float* __restrict__ b3,
    const float* __restrict__ w4, const float* __restrict__ b4,
    float* __restrict__ out)
{
    __shared__ float smf[14644];
    float* const xp  = smf;
    float* const ts  = smf + 308;
    float* const h1s = smf + 8500;
    float* const h2s = smf + 12596;
    float* const m3s = ts;
    float* const lgs = ts + 1024;

    const int tid = threadIdx.x;
    const int b   = blockIdx.x;
    for (int j = tid; j < 308; j += 256) {
        float v = 0.f;
        const int src = j - 2;
        if (src >= 0 && src < 300) v = x[b * 300 + src];
        xp[j] = v;
    }
    __syncthreads();
    const int q = tid >> 5, dd = tid & 31;
    float M = -1e30f, S = 0.f, A = 0.f;
    for (int tile = 0; tile < 23; ++tile) {
        const int pos0 = tile * 16;
        {
            const int p = tid & 15, kk0 = tid >> 4;
            const int pos = pos0 + p;
            const bool valid = (pos < 361);
            const int hh = valid ? (pos / 19) : 0;
            const int ww = valid ? (pos - hh * 19) : 0;
            #pragma unroll
            for (int i = 0; i < 16; ++i) {
                const int kk = kk0 + (i << 4);
                const int i1 = kk >> 4, j1 = kk & 15;
                float di = 0.f, ndi = 0.f;
                if (valid) {
                    const float u = xp[j1 * 19 + ww];
                    const float v = xp[i1 * 19 + hh];
                    di = u - v; ndi = di / (u + v + 1e-5f);
                }
                ts[(kk << 5) + p] = di;
                ts[(kk << 5) + 16 + p] = ndi;
            }
        }
        __syncthreads();
        {
            const int o = tid;
            float acc[16];
            const float bias = b1[o];
            #pragma unroll
            for (int p = 0; p < 16; ++p) acc[p] = bias;
            for (int k = 0; k < 512; ++k) {
                const float wv = w1[o * 512 + k];
                #pragma unroll
                for (int p = 0; p < 16; ++p) acc[p] += wv * ts[(k << 4) + p];
            }
            #pragma unroll
            for (int p = 0; p < 16; ++p) h1s[(o << 4) + p] = (acc[p] >= 0.f) ? acc[p] : 0.01f * acc[p];
        }
        __syncthreads();
        {
            const int o2 = tid & 127, pb = (tid >> 7) << 3;
            float acc[8];
            const float bias = b2[o2];
            #pragma unroll
            for (int j = 0; j < 8; ++j) acc[j] = bias;
            for (int k = 0; k < 256; ++k) {
                const float wv = w2[o2 * 256 + k];
                #pragma unroll
                for (int j = 0; j < 8; ++j) acc[j] += wv * h1s[(k << 4) + pb + j];
            }
            #pragma unroll
            for (int j = 0; j < 8; ++j) h2s[(o2 << 4) + pb + j] = (acc[j] >= 0.f) ? acc[j] : 0.01f * acc[j];
        }
        __syncthreads();
        {
            const int o3 = tid & 63, pb = (tid >> 6) << 2;
            float acc[4];
            const float bias = b3[o3];
            #pragma unroll
            for (int j = 0; j < 4; ++j) acc[j] = bias;
            for (int k = 0; k < 128; ++k) {
                const float wv = w3[o3 * 128 + k];
                #pragma unroll
                for (int j = 0; j < 4; ++j) acc[j] += wv * h2s[(k << 4) + pb + j];
            }
            #pragma unroll
            for (int j = 0; j < 4; ++j) m3s[(o3 << 4) + pb + j] = fmaxf(acc[j], 0.f);
        }
        __syncthreads();
        if (tid < 64) {
            const int o4 = tid >> 4, p = tid & 15;
            float a = b4[o4];
            for (int k = 0; k < 64; ++k) a += w4[o4 * 64 + k] * m3s[(k << 4) + p];
            a = fmaxf(a, 0.f);
            if (pos0 + p >= 361) a = -1e30f;
            lgs[(o4 << 4) + p] = a;
        }
        __syncthreads();
        if (tid < 128) {
            float l[16];
            #pragma unroll
            for (int p = 0; p < 16; ++p) l[p] = lgs[(q << 4) + p];
            float tmax = l[0];
            #pragma unroll
            for (int p = 1; p < 16; ++p) tmax = fmaxf(tmax, l[p]);
            const float newM = fmaxf(M, tmax);
            const float alpha = __expf(M - newM);
            float ssum = 0.f, asum = 0.f;
            #pragma unroll
            for (int p = 0; p < 16; ++p) {
                const float e = __expf(l[p] - newM);
                ssum += e;
                asum += e * h2s[(((q << 5) + dd) << 4) + p];
            }
            S = S * alpha + ssum; A = A * alpha + asum; M = newM;
        }
        __syncthreads();
    }
    if (tid < 128) out[(b << 7) + tid] = A / S;
}

extern "C" void kernel_launch(void* const* d_in, const int* in_sizes, int n_in,
                              void* d_out, int out_size, void* d_ws, size_t ws_size,
                              hipStream_t stream) {
    const float* x  = (const float*)d_in[0];
    const float* w1 = (const float*)d_in[1];
    const float* b1 = (const float*)d_in[2];
    const float* w2 = (const float*)d_in[3];
    const float* b2 = (const float*)d_in[4];
    const float* w3 = (const float*)d_in[5];
    const float* b3 = (const float*)d_in[6];
    const float* w4 = (const float*)d_in[7];
    const float* b4 = (const float*)d_in[8];
    float* out = (float*)d_out;

    const size_t wbytes = (size_t)WS_W_USHORTS * sizeof(ushort_t);
    ushort_t* ws = (ushort_t*)d_ws;
    const int packBlocks = (WS_W_USHORTS + 255) / 256;

    // per-NS partial sizes: A = NS*512*128 f32, S = NS*512*4 f32
    const size_t need4 = wbytes + (size_t)4 * 512 * 132 * sizeof(float);
    const size_t need2 = wbytes + (size_t)2 * 512 * 132 * sizeof(float);
    const size_t need1 = wbytes + (size_t)1 * 512 * 132 * sizeof(float);

    if (ws_size >= need4) {
        float* pA = (float*)((char*)d_ws + wbytes);
        float* pS = pA + (size_t)4 * 512 * 128;
        pack_weights<<<packBlocks, 256, 0, stream>>>(w1, w2, w3, w4, ws);
        fused_mfma<4><<<2048, 256, 0, stream>>>(x, ws, b1, b2, b3, b4, pA, pS);
        merge_out<4><<<256, 256, 0, stream>>>(pA, pS, out);
    } else if (ws_size >= need2) {
        float* pA = (float*)((char*)d_ws + wbytes);
        float* pS = pA + (size_t)2 * 512 * 128;
        pack_weights<<<packBlocks, 256, 0, stream>>>(w1, w2, w3, w4, ws);
        fused_mfma<2><<<1024, 256, 0, stream>>>(x, ws, b1, b2, b3, b4, pA, pS);
        merge_out<2><<<256, 256, 0, stream>>>(pA, pS, out);
    } else if (ws_size >= need1) {
        float* pA = (float*)((char*)d_ws + wbytes);
        float* pS = pA + (size_t)1 * 512 * 128;
        pack_weights<<<packBlocks, 256, 0, stream>>>(w1, w2, w3, w4, ws);
        fused_mfma<1><<<512, 256, 0, stream>>>(x, ws, b1, b2, b3, b4, pA, pS);
        merge_out<1><<<256, 256, 0, stream>>>(pA, pS, out);
    } else {
        fallback_fused<<<512, 256, 0, stream>>>(x, w1, b1, w2, b2, w3, b3, w4, b4, out);
    }
}

// Round 7
// 168.731 us; speedup vs baseline: 1.0429x; 1.0016x over previous
//
#include <hip/hip_runtime.h>
#include <math.h>

typedef unsigned short ushort_t;
typedef __attribute__((ext_vector_type(8))) short short8;
typedef __attribute__((ext_vector_type(4))) float f32x4;

#define NTILES 12   // 12 tiles x 32 positions = 384 >= 361

// ws ushort layout (bf16 MFMA A-fragments, lane-major 16B blocks):
//   L1 @0      : 16 outsub x 9 kstep x 64 lane x 8 = 73728   (K=288: 256 NDI + 16 u(colsum) + 16 v(-rowsum))
//   L2 @73728  :  8 outsub x 8 kstep x 64 lane x 8 = 32768
//   L3 @106496 :  4 outsub x 4 kstep x 64 lane x 8 =  8192
#define WS_W_USHORTS 114688

__device__ inline ushort_t f2bf(float f) {
    unsigned u = __float_as_uint(f);
    return (ushort_t)((u + 0x7FFFu + ((u >> 16) & 1u)) >> 16);
}
__device__ inline unsigned pkbf(float f0, float f1) {
    unsigned a = __float_as_uint(f0) + 0x8000u;
    unsigned b = __float_as_uint(f1) + 0x8000u;
    return __builtin_amdgcn_perm(b, a, 0x07060302u);
}
// leaky = max(v, 0.01v)
__device__ inline float leaky(float v) { return fmaxf(v, 0.01f * v); }

__global__ void pack_weights(const float* __restrict__ w1, const float* __restrict__ w2,
                             const float* __restrict__ w3, ushort_t* __restrict__ ws) {
    const int idx = blockIdx.x * 256 + threadIdx.x;
    if (idx >= WS_W_USHORTS) return;
    float val = 0.f;
    if (idx < 73728) {
        const int j = idx & 7, lane = (idx >> 3) & 63, blk = idx >> 9;
        const int ks = blk % 9, os = blk / 9;
        const int m = lane & 15, q = lane >> 4;
        const int row = os * 16 + m;
        if (ks < 8) {
            const int k = ks * 32 + q * 8 + j;
            const int i1 = k >> 4, j1 = k & 15;
            val = w1[row * 512 + i1 * 32 + j1 * 2 + 1];      // NDI weight (c=1)
        } else {
            const int sub = q * 8 + j;
            if (sub < 16) {                                  // u coeff: colsum of DI weights
                const int j1 = sub;
                float s = 0.f;
                #pragma unroll
                for (int i1 = 0; i1 < 16; ++i1) s += w1[row * 512 + i1 * 32 + j1 * 2];
                val = s;
            } else {                                         // v coeff: -rowsum of DI weights
                const int i1 = sub - 16;
                float s = 0.f;
                #pragma unroll
                for (int j1 = 0; j1 < 16; ++j1) s += w1[row * 512 + i1 * 32 + j1 * 2];
                val = -s;
            }
        }
    } else if (idx < 106496) {
        const int l = idx - 73728;
        const int j = l & 7, lane = (l >> 3) & 63, blk = l >> 9;
        const int ks = blk & 7, os = blk >> 3;
        const int m = lane & 15, q = lane >> 4;
        val = w2[(os * 16 + m) * 256 + ks * 32 + q * 8 + j];
    } else {
        const int l = idx - 106496;
        const int j = l & 7, lane = (l >> 3) & 63, blk = l >> 9;
        const int ks = blk & 3, os = blk >> 2;
        const int m = lane & 15, q = lane >> 4;
        val = w3[(os * 16 + m) * 128 + ks * 32 + q * 8 + j];
    }
    ws[idx] = f2bf(val);
}

// LDS (ushort units), XOR-swizzled: element (row, oct) at base + row*STR + ((oct ^ (row&7))*8)
//   ts   @0      32 x 320 (288 ch used) = 10240  } h2s aliases @0, 32x128 = 4096 (ts dead after L1;
//                                                  h2s dead after L3 -> trailing hazard covered by B4)
//   h1s  @10240  32 x 256              =  8192   } wbuf aliases @10240: [w][q][pos] 4x4x32 f32 = 2048B
//   xp   @18432  308 f32               =   616
// total 19048 ush = 38096 B -> 4 blocks/CU (VGPR must stay <= 128)
template <int NS>
__global__ __launch_bounds__(256, 3) void fused_mfma(
    const float* __restrict__ x, const ushort_t* __restrict__ ws,
    const float* __restrict__ b1, const float* __restrict__ b2,
    const float* __restrict__ b3, const float* __restrict__ b4,
    const float* __restrict__ w4,
    float* __restrict__ partA, float* __restrict__ partS)
{
    __shared__ __align__(16) ushort_t sm[19048];
    ushort_t* const ts   = sm;
    ushort_t* const h2s  = sm;                    // aliases ts
    ushort_t* const h1s  = sm + 10240;
    float*   const wbuf  = (float*)(sm + 10240);  // aliases h1s head (dead after L2 reads; B3 orders)
    float*   const xp    = (float*)(sm + 18432);

    constexpr int SH  = (NS == 4) ? 2 : ((NS == 2) ? 1 : 0);
    constexpr int TPS = (NTILES + NS - 1) / NS;
    const int tid = threadIdx.x;
    const int s   = blockIdx.x & (NS - 1);
    const int bb  = blockIdx.x >> SH;
    const int t0  = s * TPS;
    const int t1  = (t0 + TPS < NTILES) ? (t0 + TPS) : NTILES;

    const int wid  = tid >> 6;
    const int lane = tid & 63;
    const int n0   = lane & 15;
    const int qi   = lane >> 4;
    const int sx   = n0 & 7;
    const int row0 = qi * 4;

    for (int jj = tid; jj < 308; jj += 256) {
        float v = 0.f;
        const int src = jj - 2;
        if (src >= 0 && src < 300) v = x[bb * 300 + src];
        xp[jj] = v;
    }

    const short8* wf1 = (const short8*)(ws);
    const short8* wf2 = (const short8*)(ws + 73728);
    const short8* wf3 = (const short8*)(ws + 106496);

    // hoisted bias fragments + loop-invariant L3 weight frags + w4 rows (all registers)
    f32x4 bv1[4], bv2[2], bv3;
    #pragma unroll
    for (int jo = 0; jo < 4; ++jo) bv1[jo] = *(const f32x4*)&b1[(wid * 4 + jo) * 16 + row0];
    #pragma unroll
    for (int jo = 0; jo < 2; ++jo) bv2[jo] = *(const f32x4*)&b2[(wid * 2 + jo) * 16 + row0];
    bv3 = *(const f32x4*)&b3[wid * 16 + row0];
    short8 wr3[4];
    #pragma unroll
    for (int ks = 0; ks < 4; ++ks) wr3[ks] = wf3[(wid * 4 + ks) * 64 + lane];
    f32x4 w4r[4];
    #pragma unroll
    for (int q = 0; q < 4; ++q) w4r[q] = *(const f32x4*)&w4[q * 64 + wid * 16 + row0];
    const float b4s = b4[wid];

    // softmax accumulators in C-frag layout + partial e-sum
    f32x4 Afr[2] = {{0.f, 0.f, 0.f, 0.f}, {0.f, 0.f, 0.f, 0.f}};
    float Ss = 0.f;

    __syncthreads();

    for (int tile = t0; tile < t1; ++tile) {
        const int pos0 = tile * 32;

        // ---- build t tile: thread = (p = tid&31, i1b = tid>>5), i1 in {i1b, i1b+8} ----
        {
            const int p   = tid & 31;
            const int i1b = tid >> 5;
            int posg = pos0 + p; if (posg > 360) posg = 360;
            const int hh = posg / 19;
            const int ww = posg - 19 * hh;
            const int base = p * 320;
            const int psw  = p & 7;
            float u[16];
            #pragma unroll
            for (int j1 = 0; j1 < 16; ++j1) u[j1] = xp[j1 * 19 + ww];
            #pragma unroll
            for (int ii = 0; ii < 2; ++ii) {
                const int i1 = i1b + ii * 8;
                const float v = xp[i1 * 19 + hh];
                #pragma unroll
                for (int j1 = 0; j1 < 16; j1 += 2) {
                    const float nd0 = (u[j1] - v)     * __builtin_amdgcn_rcpf(u[j1] + v + 1e-5f);
                    const float nd1 = (u[j1 + 1] - v) * __builtin_amdgcn_rcpf(u[j1 + 1] + v + 1e-5f);
                    const int oct = i1 * 2 + (j1 >> 3);
                    *(unsigned*)&ts[base + ((oct ^ psw) << 3) + (j1 & 7)] = pkbf(nd0, nd1);
                }
            }
            if (i1b == 0) {  // u/v extension columns (ch 256..287)
                #pragma unroll
                for (int j1 = 0; j1 < 16; j1 += 2) {
                    const int oct = 32 + (j1 >> 3);
                    *(unsigned*)&ts[base + ((oct ^ psw) << 3) + (j1 & 7)] = pkbf(u[j1], u[j1 + 1]);
                }
                #pragma unroll
                for (int i1 = 0; i1 < 16; i1 += 2) {
                    const float v0 = xp[i1 * 19 + hh];
                    const float v1 = xp[(i1 + 1) * 19 + hh];
                    const int oct = 34 + (i1 >> 3);
                    *(unsigned*)&ts[base + ((oct ^ psw) << 3) + (i1 & 7)] = pkbf(v0, v1);
                }
            }
        }
        __syncthreads();   // B1: ts ready

        // ---- layer 1: 256 outs, K=288 (9 ksteps); wave = 4 outsubs x 2 possubs ----
        {
            f32x4 acc[4][2];
            #pragma unroll
            for (int jo = 0; jo < 4; ++jo) { acc[jo][0] = bv1[jo]; acc[jo][1] = bv1[jo]; }
            const int tb0 = n0 * 320;
            const int tb1 = tb0 + 16 * 320;
            const int wbase = wid * 2304 + lane;
            #pragma unroll 3
            for (int ks = 0; ks < 9; ++ks) {
                const int oct = ks * 4 + qi;
                const short8 bb0 = *(const short8*)&ts[tb0 + ((oct ^ sx) << 3)];
                const short8 bb1 = *(const short8*)&ts[tb1 + ((oct ^ sx) << 3)];
                #pragma unroll
                for (int jo = 0; jo < 4; ++jo) {
                    const short8 a = wf1[wbase + (jo * 9 + ks) * 64];
                    acc[jo][0] = __builtin_amdgcn_mfma_f32_16x16x32_bf16(a, bb0, acc[jo][0], 0, 0, 0);
                    acc[jo][1] = __builtin_amdgcn_mfma_f32_16x16x32_bf16(a, bb1, acc[jo][1], 0, 0, 0);
                }
            }
            #pragma unroll
            for (int jo = 0; jo < 4; ++jo) {
                const int out0 = (wid * 4 + jo) * 16 + row0;
                #pragma unroll
                for (int ps = 0; ps < 2; ++ps) {
                    const f32x4 a4 = acc[jo][ps];
                    uint2 pk;
                    pk.x = pkbf(leaky(a4.x), leaky(a4.y));
                    pk.y = pkbf(leaky(a4.z), leaky(a4.w));
                    *(uint2*)&h1s[(ps * 16 + n0) * 256 + (((out0 >> 3) ^ sx) << 3) + (out0 & 7)] = pk;
                }
            }
        }
        __syncthreads();   // B2: h1s ready; also orders L1 ts-reads before L2 h2s(=ts) writes

        // ---- layer 2: 128 outs, K=256; C-frags kept in f32 regs for the accum phase ----
        f32x4 h2f[2][2];
        {
            f32x4 acc[2][2];
            #pragma unroll
            for (int jo = 0; jo < 2; ++jo) { acc[jo][0] = bv2[jo]; acc[jo][1] = bv2[jo]; }
            const int hb0 = n0 * 256;
            const int hb1 = hb0 + 16 * 256;
            const int wbase = wid * 1024 + lane;
            #pragma unroll 4
            for (int ks = 0; ks < 8; ++ks) {
                const int oct = ks * 4 + qi;
                const short8 bb0 = *(const short8*)&h1s[hb0 + ((oct ^ sx) << 3)];
                const short8 bb1 = *(const short8*)&h1s[hb1 + ((oct ^ sx) << 3)];
                #pragma unroll
                for (int jo = 0; jo < 2; ++jo) {
                    const short8 a = wf2[wbase + (jo * 8 + ks) * 64];
                    acc[jo][0] = __builtin_amdgcn_mfma_f32_16x16x32_bf16(a, bb0, acc[jo][0], 0, 0, 0);
                    acc[jo][1] = __builtin_amdgcn_mfma_f32_16x16x32_bf16(a, bb1, acc[jo][1], 0, 0, 0);
                }
            }
            #pragma unroll
            for (int jo = 0; jo < 2; ++jo) {
                const int out0 = (wid * 2 + jo) * 16 + row0;
                #pragma unroll
                for (int ps = 0; ps < 2; ++ps) {
                    f32x4 a4 = acc[jo][ps];
                    a4.x = leaky(a4.x); a4.y = leaky(a4.y);
                    a4.z = leaky(a4.z); a4.w = leaky(a4.w);
                    h2f[jo][ps] = a4;
                    uint2 pk;
                    pk.x = pkbf(a4.x, a4.y);
                    pk.y = pkbf(a4.z, a4.w);
                    *(uint2*)&h2s[(ps * 16 + n0) * 128 + (((out0 >> 3) ^ sx) << 3) + (out0 & 7)] = pk;
                }
            }
        }
        __syncthreads();   // B3: h2s ready (also orders L2 h1s-reads before wbuf writes)

        // ---- layer 3 (all waves) + L4 partial logits in registers ----
        {
            f32x4 acc[2] = {bv3, bv3};
            const int cb0 = n0 * 128;
            const int cb1 = cb0 + 16 * 128;
            #pragma unroll
            for (int ks = 0; ks < 4; ++ks) {
                const int oct = ks * 4 + qi;
                const short8 bb0 = *(const short8*)&h2s[cb0 + ((oct ^ sx) << 3)];
                const short8 bb1 = *(const short8*)&h2s[cb1 + ((oct ^ sx) << 3)];
                acc[0] = __builtin_amdgcn_mfma_f32_16x16x32_bf16(wr3[ks], bb0, acc[0], 0, 0, 0);
                acc[1] = __builtin_amdgcn_mfma_f32_16x16x32_bf16(wr3[ks], bb1, acc[1], 0, 0, 0);
            }
            #pragma unroll
            for (int ps = 0; ps < 2; ++ps) {
                f32x4 m3 = acc[ps];
                m3.x = fmaxf(m3.x, 0.f); m3.y = fmaxf(m3.y, 0.f);
                m3.z = fmaxf(m3.z, 0.f); m3.w = fmaxf(m3.w, 0.f);
                float pl[4];
                #pragma unroll
                for (int q = 0; q < 4; ++q)
                    pl[q] = w4r[q].x * m3.x + w4r[q].y * m3.y + w4r[q].z * m3.z + w4r[q].w * m3.w;
                #pragma unroll
                for (int q = 0; q < 4; ++q) {
                    pl[q] += __shfl_xor(pl[q], 16, 64);
                    pl[q] += __shfl_xor(pl[q], 32, 64);
                }
                if (qi == 0) {
                    #pragma unroll
                    for (int q = 0; q < 4; ++q)
                        wbuf[(wid * 4 + q) * 32 + ps * 16 + n0] = pl[q];
                }
            }
        }
        __syncthreads();   // B4: wbuf ready; h2s(=ts) dead -> next build safe

        // ---- exp + accumulate (every thread; 4x redundant exp over qi, no extra barrier) ----
        {
            #pragma unroll
            for (int ps = 0; ps < 2; ++ps) {
                const int pos = ps * 16 + n0;
                float lg = wbuf[(0 * 4 + wid) * 32 + pos] + wbuf[(1 * 4 + wid) * 32 + pos]
                         + wbuf[(2 * 4 + wid) * 32 + pos] + wbuf[(3 * 4 + wid) * 32 + pos] + b4s;
                lg = fmaxf(lg, 0.f);
                const float e = ((pos0 + pos) > 360) ? 0.f : __expf(lg);
                #pragma unroll
                for (int jo = 0; jo < 2; ++jo) {
                    Afr[jo].x += e * h2f[jo][ps].x;
                    Afr[jo].y += e * h2f[jo][ps].y;
                    Afr[jo].z += e * h2f[jo][ps].z;
                    Afr[jo].w += e * h2f[jo][ps].w;
                }
                Ss += e;
            }
        }
        // no trailing barrier: accum reads wbuf; next-tile h1s writes are after B2(next)
    }

    // cross-lane reduce over n0 (positions) via shfl butterfly
    #pragma unroll
    for (int bit = 1; bit < 16; bit <<= 1) {
        #pragma unroll
        for (int jo = 0; jo < 2; ++jo) {
            Afr[jo].x += __shfl_xor(Afr[jo].x, bit, 64);
            Afr[jo].y += __shfl_xor(Afr[jo].y, bit, 64);
            Afr[jo].z += __shfl_xor(Afr[jo].z, bit, 64);
            Afr[jo].w += __shfl_xor(Afr[jo].w, bit, 64);
        }
        Ss += __shfl_xor(Ss, bit, 64);
    }
    if (n0 == 0) {
        const int pbA = (s * 512 + bb) * 128;
        #pragma unroll
        for (int jo = 0; jo < 2; ++jo) {
            const int ch0 = (wid * 2 + jo) * 16 + qi * 4;
            partA[pbA + ch0]     = Afr[jo].x;
            partA[pbA + ch0 + 1] = Afr[jo].y;
            partA[pbA + ch0 + 2] = Afr[jo].z;
            partA[pbA + ch0 + 3] = Afr[jo].w;
        }
        if (qi == 0) partS[(s * 512 + bb) * 4 + wid] = Ss;
    }
}

template <int NS>
__global__ void merge_out(const float* __restrict__ partA, const float* __restrict__ partS,
                          float* __restrict__ out) {
    const int idx = blockIdx.x * 256 + threadIdx.x;
    if (idx >= 512 * 128) return;
    const int bb = idx >> 7, ch = idx & 127;
    const int q = ch >> 5;
    float Sf = 0.f, Af = 0.f;
    #pragma unroll
    for (int s = 0; s < NS; ++s) {
        Af += partA[(s * 512 + bb) * 128 + ch];
        Sf += partS[(s * 512 + bb) * 4 + q];
    }
    out[idx] = Af / Sf;
}

// ---------------- f32 scalar fallback (known-correct, ws-free) ----------------
__global__ __launch_bounds__(256, 2) void fallback_fused(
    const float* __restrict__ x,
    const float* __restrict__ w1, const float* __restrict__ b1,
    const float* __restrict__ w2, const float* __restrict__ b2,
    const float* __restrict__ w3, const float* __restrict__ b3,
    const float* __restrict__ w4, const float* __restrict__ b4,
    float* __restrict__ out)
{
    __shared__ float smf[14644];
    float* const xp  = smf;
    float* const ts  = smf + 308;
    float* const h1s = smf + 8500;
    float* const h2s = smf + 12596;
    float* const m3s = ts;
    float* const lgs = ts + 1024;

    const int tid = threadIdx.x;
    const int b   = blockIdx.x;
    for (int j = tid; j < 308; j += 256) {
        float v = 0.f;
        const int src = j - 2;
        if (src >= 0 && src < 300) v = x[b * 300 + src];
        xp[j] = v;
    }
    __syncthreads();
    const int q = tid >> 5, dd = tid & 31;
    float M = -1e30f, S = 0.f, A = 0.f;
    for (int tile = 0; tile < 23; ++tile) {
        const int pos0 = tile * 16;
        {
            const int p = tid & 15, kk0 = tid >> 4;
            const int pos = pos0 + p;
            const bool valid = (pos < 361);
            const int hh = valid ? (pos / 19) : 0;
            const int ww = valid ? (pos - hh * 19) : 0;
            #pragma unroll
            for (int i = 0; i < 16; ++i) {
                const int kk = kk0 + (i << 4);
                const int i1 = kk >> 4, j1 = kk & 15;
                float di = 0.f, ndi = 0.f;
                if (valid) {
                    const float u = xp[j1 * 19 + ww];
                    const float v = xp[i1 * 19 + hh];
                    di = u - v; ndi = di / (u + v + 1e-5f);
                }
                ts[(kk << 5) + p] = di;
                ts[(kk << 5) + 16 + p] = ndi;
            }
        }
        __syncthreads();
        {
            const int o = tid;
            float acc[16];
            const float bias = b1[o];
            #pragma unroll
            for (int p = 0; p < 16; ++p) acc[p] = bias;
            for (int k = 0; k < 512; ++k) {
                const float wv = w1[o * 512 + k];
                #pragma unroll
                for (int p = 0; p < 16; ++p) acc[p] += wv * ts[(k << 4) + p];
            }
            #pragma unroll
            for (int p = 0; p < 16; ++p) h1s[(o << 4) + p] = (acc[p] >= 0.f) ? acc[p] : 0.01f * acc[p];
        }
        __syncthreads();
        {
            const int o2 = tid & 127, pb = (tid >> 7) << 3;
            float acc[8];
            const float bias = b2[o2];
            #pragma unroll
            for (int j = 0; j < 8; ++j) acc[j] = bias;
            for (int k = 0; k < 256; ++k) {
                const float wv = w2[o2 * 256 + k];
                #pragma unroll
                for (int j = 0; j < 8; ++j) acc[j] += wv * h1s[(k << 4) + pb + j];
            }
            #pragma unroll
            for (int j = 0; j < 8; ++j) h2s[(o2 << 4) + pb + j] = (acc[j] >= 0.f) ? acc[j] : 0.01f * acc[j];
        }
        __syncthreads();
        {
            const int o3 = tid & 63, pb = (tid >> 6) << 2;
            float acc[4];
            const float bias = b3[o3];
            #pragma unroll
            for (int j = 0; j < 4; ++j) acc[j] = bias;
            for (int k = 0; k < 128; ++k) {
                const float wv = w3[o3 * 128 + k];
                #pragma unroll
                for (int j = 0; j < 4; ++j) acc[j] += wv * h2s[(k << 4) + pb + j];
            }
            #pragma unroll
            for (int j = 0; j < 4; ++j) m3s[(o3 << 4) + pb + j] = fmaxf(acc[j], 0.f);
        }
        __syncthreads();
        if (tid < 64) {
            const int o4 = tid >> 4, p = tid & 15;
            float a = b4[o4];
            for (int k = 0; k < 64; ++k) a += w4[o4 * 64 + k] * m3s[(k << 4) + p];
            a = fmaxf(a, 0.f);
            if (pos0 + p >= 361) a = -1e30f;
            lgs[(o4 << 4) + p] = a;
        }
        __syncthreads();
        if (tid < 128) {
            float l[16];
            #pragma unroll
            for (int p = 0; p < 16; ++p) l[p] = lgs[(q << 4) + p];
            float tmax = l[0];
            #pragma unroll
            for (int p = 1; p < 16; ++p) tmax = fmaxf(tmax, l[p]);
            const float newM = fmaxf(M, tmax);
            const float alpha = __expf(M - newM);
            float ssum = 0.f, asum = 0.f;
            #pragma unroll
            for (int p = 0; p < 16; ++p) {
                const float e = __expf(l[p] - newM);
                ssum += e;
                asum += e * h2s[(((q << 5) + dd) << 4) + p];
            }
            S = S * alpha + ssum; A = A * alpha + asum; M = newM;
        }
        __syncthreads();
    }
    if (tid < 128) out[(b << 7) + tid] = A / S;
}

extern "C" void kernel_launch(void* const* d_in, const int* in_sizes, int n_in,
                              void* d_out, int out_size, void* d_ws, size_t ws_size,
                              hipStream_t stream) {
    const float* x  = (const float*)d_in[0];
    const float* w1 = (const float*)d_in[1];
    const float* b1 = (const float*)d_in[2];
    const float* w2 = (const float*)d_in[3];
    const float* b2 = (const float*)d_in[4];
    const float* w3 = (const float*)d_in[5];
    const float* b3 = (const float*)d_in[6];
    const float* w4 = (const float*)d_in[7];
    const float* b4 = (const float*)d_in[8];
    float* out = (float*)d_out;

    const size_t wbytes = (size_t)WS_W_USHORTS * sizeof(ushort_t);
    ushort_t* ws = (ushort_t*)d_ws;
    const int packBlocks = (WS_W_USHORTS + 255) / 256;

    const size_t need4 = wbytes + (size_t)4 * 512 * 132 * sizeof(float);
    const size_t need2 = wbytes + (size_t)2 * 512 * 132 * sizeof(float);
    const size_t need1 = wbytes + (size_t)1 * 512 * 132 * sizeof(float);

    if (ws_size >= need4) {
        float* pA = (float*)((char*)d_ws + wbytes);
        float* pS = pA + (size_t)4 * 512 * 128;
        pack_weights<<<packBlocks, 256, 0, stream>>>(w1, w2, w3, ws);
        fused_mfma<4><<<2048, 256, 0, stream>>>(x, ws, b1, b2, b3, b4, w4, pA, pS);
        merge_out<4><<<256, 256, 0, stream>>>(pA, pS, out);
    } else if (ws_size >= need2) {
        float* pA = (float*)((char*)d_ws + wbytes);
        float* pS = pA + (size_t)2 * 512 * 128;
        pack_weights<<<packBlocks, 256, 0, stream>>>(w1, w2, w3, ws);
        fused_mfma<2><<<1024, 256, 0, stream>>>(x, ws, b1, b2, b3, b4, w4, pA, pS);
        merge_out<2><<<256, 256, 0, stream>>>(pA, pS, out);
    } else if (ws_size >= need1) {
        float* pA = (float*)((char*)d_ws + wbytes);
        float* pS = pA + (size_t)1 * 512 * 128;
        pack_weights<<<packBlocks, 256, 0, stream>>>(w1, w2, w3, ws);
        fused_mfma<1><<<512, 256, 0, stream>>>(x, ws, b1, b2, b3, b4, w4, pA, pS);
        merge_out<1><<<256, 256, 0, stream>>>(pA, pS, out);
    } else {
        fallback_fused<<<512, 256, 0, stream>>>(x, w1, b1, w2, b2, w3, b3, w4, b4, out);
    }
}